// Round 9
// baseline (48.311 us; speedup 1.0000x reference)
//
#include <hip/hip_runtime.h>
#include <math.h>

#define FDIM  100
#define ODIM  180
#define NFILT (FDIM * ODIM)    // 18000
#define HTOT  512
#define WTOT  512
#define TILE  32               // 32x32 pixel tile per (tile,slice) block
#define REG   48               // staged region = TILE + 16
#define LDSW  49
#define NSLICE 8
#define SLICE_SZ 2250          // 18000/8 -> per-XCD-resident slice
#define NTILE 256              // (512/32)^2
#define NBLK  (NTILE * NSLICE) // 2048 blocks
#define RSTRIDE 320            // repacked floats per filter (1280 B, 64-B aligned)
#define TEMPERATURE 20.0f
#define THRESHOLD   55.0f

typedef float f32x4 __attribute__((ext_vector_type(4)));

// ws layout (bytes):
//   [0, 23040000)            : repacked filterbank, 18000 x 320 floats
//   [23040000, 23040000+16K) : float2 partial[2048]
//   [+16K, +16K+8)           : final float {min, max}
#define WS_PARTIAL 23040000
#define WS_MMF     (WS_PARTIAL + 16384)

// Repack: rk[f*320 + J*64 + 4l + i] = fb[f*289 + 64J + 16i + l]  (0 if e>288).
// Lane-permuted so the main kernel's b128 quad (i=0..3) maps to patch elements
// e = 16*(4J+i) + l  -> stride-1 across lanes -> conflict-free LDS reads.
__global__ __launch_bounds__(256) void repack_fb(
    const float* __restrict__ fb,
    float*       __restrict__ rfb)
{
    const int q = blockIdx.x * 256 + threadIdx.x;     // one float4 quad per thread
    if (q >= NFILT * (RSTRIDE / 4)) return;
    const int f = q / (RSTRIDE / 4);
    const int r = q - f * (RSTRIDE / 4);              // r = J*16 + l
    const int J = r >> 4, l = r & 15;
    const float* __restrict__ src = fb + (size_t)f * 289;
    f32x4 v;
    #pragma unroll
    for (int i = 0; i < 4; ++i) {
        const int e = 64 * J + 16 * i + l;
        v[i] = (e <= 288) ? src[e] : 0.f;
    }
    reinterpret_cast<f32x4*>(rfb)[q] = v;
}

__global__ __launch_bounds__(256) void filter_sliced(
    const float* __restrict__ x,
    const int*   __restrict__ freq,
    const int*   __restrict__ orient,
    const float* __restrict__ rfb,
    float*       __restrict__ y,
    float2*      __restrict__ partial)
{
    __shared__ float tile[REG][LDSW];          // 48 x 49 floats = 9408 B
    __shared__ int   sidx[TILE * TILE];        // 4096 B
    __shared__ unsigned short sel[TILE * TILE];// 2048 B
    __shared__ unsigned int nsel;

    const int gid   = blockIdx.x;
    const int slice = gid & (NSLICE - 1);
    const int t     = gid >> 3;                // tile id 0..255
    const int bx    = t & 15, by = t >> 4;
    const int tid   = threadIdx.x;

    if (tid == 0) nsel = 0;
    __syncthreads();

    // pass 1: per-pixel filter index + compaction of this slice's pixels
    const int lo = slice * SLICE_SZ;
    #pragma unroll
    for (int k = 0; k < 4; ++k) {
        const int p  = tid + k * 256;
        const int pr = p >> 5, pc = p & 31;
        const int pid = (by * TILE + pr) * WTOT + bx * TILE + pc;
        int f0 = freq[pid] - 1;
        int o0 = orient[pid] - 1;
        f0 = f0 < 0 ? 0 : (f0 > FDIM - 1 ? FDIM - 1 : f0);
        o0 = o0 < 0 ? 0 : (o0 > ODIM - 1 ? ODIM - 1 : o0);
        const int idx = f0 * ODIM + o0;
        sidx[p] = idx;
        if (idx >= lo && idx < lo + SLICE_SZ) {
            unsigned int s = atomicAdd(&nsel, 1u);
            sel[s] = (unsigned short)p;
        }
    }

    // stage 48x48 input region (zero-padded at image borders)
    const int h0 = by * TILE - 8;
    const int w0 = bx * TILE - 8;
    for (int i = tid; i < REG * REG; i += 256) {
        const int r = i / REG, c = i - r * REG;
        const int gh = h0 + r, gw = w0 + c;
        float v = 0.f;
        if (gh >= 0 && gh < HTOT && gw >= 0 && gw < WTOT)
            v = x[gh * WTOT + gw];
        tile[r][c] = v;
    }
    __syncthreads();

    const unsigned int m = nsel;
    const int l  = tid & 15;                   // lane within quarter-wave
    const int qw = tid >> 4;                   // quarter-wave id

    // per-lane patch offsets for j=0..19 (element e = 16j + l, clamped to 288;
    // clamped lanes broadcast-read one slot and multiply by the zero pad)
    int offs[20];
    #pragma unroll
    for (int j = 0; j < 20; ++j) {
        int e = j * 16 + l;
        e = e > 288 ? 288 : e;
        offs[j] = (e / 17) * LDSW + (e % 17);
    }

    float mn = 3.4e38f, mx = -3.4e38f;

    for (unsigned int s = qw; s < m; s += 16) {
        const int tp  = sel[s];
        const int ppy = tp >> 5, ppx = tp & 31;
        const float* __restrict__ kf = rfb + (size_t)sidx[tp] * RSTRIDE;

        // 5 aligned b128 filter loads (one 256-B / 4-line window per qw round)
        f32x4 kq[5];
        #pragma unroll
        for (int J = 0; J < 5; ++J)
            kq[J] = *reinterpret_cast<const f32x4*>(kf + J * 64 + 4 * l);

        const float* __restrict__ base = &tile[ppy][ppx];
        float a0 = 0.f, a1 = 0.f, a2 = 0.f, a3 = 0.f;
        #pragma unroll
        for (int J = 0; J < 5; ++J) {
            a0 = fmaf(kq[J].x, base[offs[4 * J + 0]], a0);
            a1 = fmaf(kq[J].y, base[offs[4 * J + 1]], a1);
            a2 = fmaf(kq[J].z, base[offs[4 * J + 2]], a2);
            a3 = fmaf(kq[J].w, base[offs[4 * J + 3]], a3);
        }
        float acc = (a0 + a1) + (a2 + a3);

        // butterfly sum over the 16-lane group
        #pragma unroll
        for (int off = 8; off; off >>= 1)
            acc += __shfl_xor(acc, off, 64);

        if (l == 0)
            y[(by * TILE + ppy) * WTOT + bx * TILE + ppx] = acc;
        mn = fminf(mn, acc);
        mx = fmaxf(mx, acc);
    }

    // ---- block min/max reduce, then ONE plain store to a unique slot ----
    #pragma unroll
    for (int off = 32; off > 0; off >>= 1) {
        mn = fminf(mn, __shfl_down(mn, off, 64));
        mx = fmaxf(mx, __shfl_down(mx, off, 64));
    }
    __shared__ float smn[4], smx[4];
    const int wid = tid >> 6, lane = tid & 63;
    if (lane == 0) { smn[wid] = mn; smx[wid] = mx; }
    __syncthreads();
    if (tid == 0) {
        float bmn = smn[0], bmx = smx[0];
        #pragma unroll
        for (int i = 1; i < 4; ++i) {
            bmn = fminf(bmn, smn[i]);
            bmx = fmaxf(bmx, smx[i]);
        }
        partial[gid] = make_float2(bmn, bmx);
    }
}

// fold the 2048 per-block partials into plain floats {min, max}
__global__ __launch_bounds__(256) void reduce_mm(
    const float2* __restrict__ partial,
    float* __restrict__ mmf)
{
    const int tid = threadIdx.x;
    float mn = 3.4e38f, mx = -3.4e38f;
    for (int i = tid; i < NBLK; i += 256) {
        const float2 p = partial[i];
        mn = fminf(mn, p.x);
        mx = fmaxf(mx, p.y);
    }
    #pragma unroll
    for (int off = 32; off > 0; off >>= 1) {
        mn = fminf(mn, __shfl_down(mn, off, 64));
        mx = fmaxf(mx, __shfl_down(mx, off, 64));
    }
    __shared__ float smn[4], smx[4];
    const int wid = tid >> 6, lane = tid & 63;
    if (lane == 0) { smn[wid] = mn; smx[wid] = mx; }
    __syncthreads();
    if (tid == 0) {
        float bmn = smn[0], bmx = smx[0];
        #pragma unroll
        for (int i = 1; i < 4; ++i) {
            bmn = fminf(bmn, smn[i]);
            bmx = fmaxf(bmx, smx[i]);
        }
        mmf[0] = bmn;
        mmf[1] = bmx;
    }
}

__global__ __launch_bounds__(256) void filter_final(
    float* __restrict__ y,
    const float* __restrict__ mmf)
{
    const int i = blockIdx.x * 256 + threadIdx.x;
    const float ymin = mmf[0];
    const float ymax = mmf[1];
    const float rng  = fmaxf(ymax - ymin, 1e-8f);

    const float v  = y[i];
    const float o1 = 100.f * (v - ymin) / rng;                     // in [0,100]
    const float s  = 100.f / (1.f + expf(-(TEMPERATURE * (o1 * 0.01f - THRESHOLD * 0.01f))));

    // analytic post-sigmoid extrema: o1 hits exactly 0 and 100 at argmin/argmax
    const float smin = 100.f / (1.f + expf( 11.f));   // 100*sigmoid(-11)
    const float smax = 100.f / (1.f + expf(-9.f));    // 100*sigmoid(+9)
    const float srng = fmaxf(smax - smin, 1e-8f);

    y[i] = 100.f * (s - smin) / srng;
}

extern "C" void kernel_launch(void* const* d_in, const int* in_sizes, int n_in,
                              void* d_out, int out_size, void* d_ws, size_t ws_size,
                              hipStream_t stream) {
    const float* x      = (const float*)d_in[0];
    const int*   freq   = (const int*)d_in[1];
    const int*   orient = (const int*)d_in[2];
    const float* fb     = (const float*)d_in[3];
    float*       out    = (float*)d_out;                       // doubles as y scratch
    float*       rfb    = (float*)d_ws;                        // repacked filterbank
    float2*      partial = (float2*)((char*)d_ws + WS_PARTIAL);
    float*       mmf    = (float*)((char*)d_ws + WS_MMF);

    // per-call repack: 18000 x 80 quads, one per thread
    const int nq = NFILT * (RSTRIDE / 4);
    repack_fb<<<(nq + 255) / 256, 256, 0, stream>>>(fb, rfb);

    // 256 tiles x 8 slices; consecutive gid = same tile across the 8 XCDs
    filter_sliced<<<dim3(NBLK), 256, 0, stream>>>(x, freq, orient, rfb, out, partial);

    reduce_mm<<<1, 256, 0, stream>>>(partial, mmf);

    filter_final<<<(HTOT * WTOT) / 256, 256, 0, stream>>>(out, mmf);
}

// Round 10
// 42.786 us; speedup vs baseline: 1.1291x; 1.1291x over previous
//
#include <hip/hip_runtime.h>
#include <math.h>

#define FDIM  100
#define ODIM  180
#define HTOT  512
#define WTOT  512
#define TILE  32               // 32x32 pixel tile per (tile,slice) block
#define REG   48               // staged region = TILE + 16
#define LDSW  49
#define NSLICE 8
#define SLICE_SZ 2250          // 18000/8 -> per-XCD-resident 2.6 MB slice
#define NTILE 256              // (512/32)^2
#define NBLK  (NTILE * NSLICE) // 2048 blocks
#define TEMPERATURE 20.0f
#define THRESHOLD   55.0f

typedef float f32x4 __attribute__((ext_vector_type(4)));

// ws layout (bytes): [0, 16384) : float2 partial[2048] — all written every call
__global__ __launch_bounds__(256) void filter_sliced(
    const float* __restrict__ x,
    const int*   __restrict__ freq,
    const int*   __restrict__ orient,
    const float* __restrict__ fb,
    float*       __restrict__ y,
    float2*      __restrict__ partial)
{
    __shared__ float tile[REG][LDSW];          // 48 x 49 floats = 9408 B
    __shared__ int   sidx[TILE * TILE];        // 4096 B
    __shared__ unsigned short sel[TILE * TILE];// 2048 B
    __shared__ unsigned int nsel;

    const int gid   = blockIdx.x;
    const int slice = gid & (NSLICE - 1);
    const int t     = gid >> 3;                // tile id 0..255
    const int bx    = t & 15, by = t >> 4;
    const int tid   = threadIdx.x;
    const int lane  = tid & 63;

    if (tid == 0) nsel = 0;
    __syncthreads();

    // pass 1: per-pixel filter index + wave-aggregated compaction (1 atomic/wave/pass)
    const int lo = slice * SLICE_SZ;
    #pragma unroll
    for (int k = 0; k < 4; ++k) {
        const int p  = tid + k * 256;
        const int pr = p >> 5, pc = p & 31;
        const int pid = (by * TILE + pr) * WTOT + bx * TILE + pc;
        int f0 = freq[pid] - 1;
        int o0 = orient[pid] - 1;
        f0 = f0 < 0 ? 0 : (f0 > FDIM - 1 ? FDIM - 1 : f0);
        o0 = o0 < 0 ? 0 : (o0 > ODIM - 1 ? ODIM - 1 : o0);
        const int idx = f0 * ODIM + o0;
        sidx[p] = idx;
        const bool want = (idx >= lo && idx < lo + SLICE_SZ);
        const unsigned long long mask = __ballot(want);
        unsigned int base = 0;
        if (lane == 0) base = atomicAdd(&nsel, (unsigned int)__popcll(mask));
        base = __shfl(base, 0, 64);
        if (want) {
            const int pos = __popcll(mask & ((1ULL << lane) - 1ULL));
            sel[base + pos] = (unsigned short)p;
        }
    }

    // stage 48x48 input region (zero-padded at image borders)
    const int h0 = by * TILE - 8;
    const int w0 = bx * TILE - 8;
    for (int i = tid; i < REG * REG; i += 256) {
        const int r = i / REG, c = i - r * REG;
        const int gh = h0 + r, gw = w0 + c;
        float v = 0.f;
        if (gh >= 0 && gh < HTOT && gw >= 0 && gw < WTOT)
            v = x[gh * WTOT + gw];
        tile[r][c] = v;
    }
    __syncthreads();

    const unsigned int m = nsel;
    const int l  = tid & 15;                   // lane within quarter-wave
    const int qw = tid >> 4;                   // quarter-wave id

    int offs[18];
    #pragma unroll
    for (int j = 0; j < 18; ++j) {
        const int e = j * 16 + l;
        offs[j] = (e / 17) * LDSW + (e % 17);
    }

    float mn = 3.4e38f, mx = -3.4e38f;

    // software-pipelined: prefetch trip s+16's filter while computing trip s
    float kv[19];
    int   cur_tp = 0;
    if (qw < (int)m) {
        cur_tp = sel[qw];
        const float* __restrict__ kf = fb + (size_t)sidx[cur_tp] * 289;
        #pragma unroll
        for (int j = 0; j < 18; ++j) kv[j] = kf[j * 16 + l];
        kv[18] = kf[288];
    }

    for (unsigned int s = qw; s < m; s += 16) {
        // prefetch next trip
        const unsigned int sn = s + 16;
        float kn[19];
        int   nxt_tp = 0;
        if (sn < m) {
            nxt_tp = sel[sn];
            const float* __restrict__ kf = fb + (size_t)sidx[nxt_tp] * 289;
            #pragma unroll
            for (int j = 0; j < 18; ++j) kn[j] = kf[j * 16 + l];
            kn[18] = kf[288];
        }

        // compute current trip
        const int ppy = cur_tp >> 5, ppx = cur_tp & 31;
        const float* __restrict__ base = &tile[ppy][ppx];
        float a0 = 0.f, a1 = 0.f, a2 = 0.f, a3 = 0.f;
        #pragma unroll
        for (int j = 0; j < 16; j += 4) {
            a0 = fmaf(kv[j    ], base[offs[j    ]], a0);
            a1 = fmaf(kv[j + 1], base[offs[j + 1]], a1);
            a2 = fmaf(kv[j + 2], base[offs[j + 2]], a2);
            a3 = fmaf(kv[j + 3], base[offs[j + 3]], a3);
        }
        a0 = fmaf(kv[16], base[offs[16]], a0);
        a1 = fmaf(kv[17], base[offs[17]], a1);
        float acc = (a0 + a1) + (a2 + a3);
        if (l == 0) acc = fmaf(kv[18], base[16 * LDSW + 16], acc);  // e = 288 tail

        // butterfly sum over the 16-lane group
        #pragma unroll
        for (int off = 8; off; off >>= 1)
            acc += __shfl_xor(acc, off, 64);

        if (l == 0)
            y[(by * TILE + ppy) * WTOT + bx * TILE + ppx] = acc;
        mn = fminf(mn, acc);
        mx = fmaxf(mx, acc);

        // rotate prefetched registers
        if (sn < m) {
            cur_tp = nxt_tp;
            #pragma unroll
            for (int j = 0; j < 19; ++j) kv[j] = kn[j];
        }
    }

    // ---- block min/max reduce, then ONE plain store to a unique slot ----
    #pragma unroll
    for (int off = 32; off > 0; off >>= 1) {
        mn = fminf(mn, __shfl_down(mn, off, 64));
        mx = fmaxf(mx, __shfl_down(mx, off, 64));
    }
    __shared__ float smn[4], smx[4];
    const int wid = tid >> 6;
    if (lane == 0) { smn[wid] = mn; smx[wid] = mx; }
    __syncthreads();
    if (tid == 0) {
        float bmn = smn[0], bmx = smx[0];
        #pragma unroll
        for (int i = 1; i < 4; ++i) {
            bmn = fminf(bmn, smn[i]);
            bmx = fmaxf(bmx, smx[i]);
        }
        partial[gid] = make_float2(bmn, bmx);
    }
}

// fused: re-reduce the 2048 partials (16 KB, L2-hit) + transform 4 px/thread
__global__ __launch_bounds__(256) void filter_final(
    float* __restrict__ y,
    const float2* __restrict__ partial)
{
    const int tid = threadIdx.x;
    float mn = 3.4e38f, mx = -3.4e38f;
    for (int i = tid; i < NBLK; i += 256) {
        const float2 p = partial[i];
        mn = fminf(mn, p.x);
        mx = fmaxf(mx, p.y);
    }
    #pragma unroll
    for (int off = 32; off > 0; off >>= 1) {
        mn = fminf(mn, __shfl_down(mn, off, 64));
        mx = fmaxf(mx, __shfl_down(mx, off, 64));
    }
    __shared__ float smn[4], smx[4];
    const int wid = tid >> 6, lane = tid & 63;
    if (lane == 0) { smn[wid] = mn; smx[wid] = mx; }
    __syncthreads();
    __shared__ float sfin[2];
    if (tid == 0) {
        float bmn = smn[0], bmx = smx[0];
        #pragma unroll
        for (int i = 1; i < 4; ++i) {
            bmn = fminf(bmn, smn[i]);
            bmx = fmaxf(bmx, smx[i]);
        }
        sfin[0] = bmn; sfin[1] = bmx;
    }
    __syncthreads();

    const float ymin = sfin[0];
    const float rng  = fmaxf(sfin[1] - ymin, 1e-8f);
    const float smin = 100.f / (1.f + expf( 11.f));   // 100*sigmoid(-11)
    const float smax = 100.f / (1.f + expf(-9.f));    // 100*sigmoid(+9)
    const float srng = fmaxf(smax - smin, 1e-8f);

    const int base = blockIdx.x * 1024 + tid * 4;
    f32x4 v = *reinterpret_cast<const f32x4*>(&y[base]);
    #pragma unroll
    for (int i = 0; i < 4; ++i) {
        const float o1 = 100.f * (v[i] - ymin) / rng;            // in [0,100]
        const float s  = 100.f / (1.f + expf(-(TEMPERATURE * (o1 * 0.01f - THRESHOLD * 0.01f))));
        v[i] = 100.f * (s - smin) / srng;
    }
    *reinterpret_cast<f32x4*>(&y[base]) = v;
}

extern "C" void kernel_launch(void* const* d_in, const int* in_sizes, int n_in,
                              void* d_out, int out_size, void* d_ws, size_t ws_size,
                              hipStream_t stream) {
    const float* x      = (const float*)d_in[0];
    const int*   freq   = (const int*)d_in[1];
    const int*   orient = (const int*)d_in[2];
    const float* fb     = (const float*)d_in[3];
    float*       out    = (float*)d_out;       // doubles as y scratch
    float2*      partial = (float2*)d_ws;      // 2048 per-block {min,max}

    // 256 tiles x 8 slices; consecutive gid = same tile across the 8 XCDs
    filter_sliced<<<dim3(NBLK), 256, 0, stream>>>(x, freq, orient, fb, out, partial);

    // 256 blocks x 256 threads x 4 px; each block inlines the partial-reduce
    filter_final<<<(HTOT * WTOT) / 1024, 256, 0, stream>>>(out, partial);
}

// Round 11
// 34.133 us; speedup vs baseline: 1.4154x; 1.2535x over previous
//
#include <hip/hip_runtime.h>
#include <math.h>

#define FDIM  100
#define ODIM  180
#define HTOT  512
#define WTOT  512
#define TILE  32               // 32x32 pixel tile per (tile,slice) block
#define REG   48               // staged region = TILE + 16
#define LDSW  49
#define NSLICE 8
#define SLICE_SZ 2250          // 18000/8 -> per-XCD-resident 2.6 MB slice
#define NTILE 256              // (512/32)^2
#define NBLK  (NTILE * NSLICE) // 2048 blocks
#define TEMPERATURE 20.0f
#define THRESHOLD   55.0f

typedef float f32x4 __attribute__((ext_vector_type(4)));

// ws layout (bytes): [0, 16384) : float2 partial[2048] — all written every call
__global__ __launch_bounds__(256) void filter_sliced(
    const float* __restrict__ x,
    const int*   __restrict__ freq,
    const int*   __restrict__ orient,
    const float* __restrict__ fb,
    float*       __restrict__ y,
    float2*      __restrict__ partial)
{
    __shared__ float tile[REG][LDSW];          // 48 x 49 floats = 9408 B
    __shared__ int   sel[TILE * TILE];         // packed (idx<<10)|p, 4096 B
    __shared__ unsigned int nsel;

    const int gid   = blockIdx.x;
    const int slice = gid & (NSLICE - 1);
    const int t     = gid >> 3;                // tile id 0..255
    const int bx    = t & 15, by = t >> 4;
    const int tid   = threadIdx.x;
    const int lane  = tid & 63;

    if (tid == 0) nsel = 0;
    __syncthreads();

    // pass 1: per-pixel filter index + wave-aggregated compaction (1 atomic/wave/pass)
    const int lo = slice * SLICE_SZ;
    #pragma unroll
    for (int k = 0; k < 4; ++k) {
        const int p  = tid + k * 256;
        const int pr = p >> 5, pc = p & 31;
        const int pid = (by * TILE + pr) * WTOT + bx * TILE + pc;
        int f0 = freq[pid] - 1;
        int o0 = orient[pid] - 1;
        f0 = f0 < 0 ? 0 : (f0 > FDIM - 1 ? FDIM - 1 : f0);
        o0 = o0 < 0 ? 0 : (o0 > ODIM - 1 ? ODIM - 1 : o0);
        const int idx = f0 * ODIM + o0;
        const bool want = (idx >= lo && idx < lo + SLICE_SZ);
        const unsigned long long mask = __ballot(want);
        unsigned int base = 0;
        if (lane == 0) base = atomicAdd(&nsel, (unsigned int)__popcll(mask));
        base = __shfl(base, 0, 64);
        if (want) {
            const int pos = __popcll(mask & ((1ULL << lane) - 1ULL));
            sel[base + pos] = (idx << 10) | p;
        }
    }

    // stage 48x48 input region (zero-padded at image borders)
    const int h0 = by * TILE - 8;
    const int w0 = bx * TILE - 8;
    for (int i = tid; i < REG * REG; i += 256) {
        const int r = i / REG, c = i - r * REG;
        const int gh = h0 + r, gw = w0 + c;
        float v = 0.f;
        if (gh >= 0 && gh < HTOT && gw >= 0 && gw < WTOT)
            v = x[gh * WTOT + gw];
        tile[r][c] = v;
    }
    __syncthreads();

    const unsigned int m = nsel;
    const int l  = tid & 15;                   // lane within quarter-wave
    const int qw = tid >> 4;                   // quarter-wave id

    int offs[18];
    #pragma unroll
    for (int j = 0; j < 18; ++j) {
        const int e = j * 16 + l;
        offs[j] = (e / 17) * LDSW + (e % 17);
    }

    float mn = 3.4e38f, mx = -3.4e38f;

    // each quarter-wave takes every 16th selected pixel (avg ~8 each);
    // batch the 19 filter loads, let the compiler schedule (R8 form — the
    // explicit rotate-pipeline variant regressed to 43 us, R10 post-mortem)
    for (unsigned int s = qw; s < m; s += 16) {
        const int packed = sel[s];
        const int tp  = packed & 1023;
        const int ppy = tp >> 5, ppx = tp & 31;
        const float* __restrict__ kf = fb + (size_t)(packed >> 10) * 289;

        float kv[18];
        #pragma unroll
        for (int j = 0; j < 18; ++j) kv[j] = kf[j * 16 + l];
        const float kt = kf[288];

        const float* __restrict__ base = &tile[ppy][ppx];
        float a0 = 0.f, a1 = 0.f, a2 = 0.f, a3 = 0.f;
        #pragma unroll
        for (int j = 0; j < 16; j += 4) {
            a0 = fmaf(kv[j    ], base[offs[j    ]], a0);
            a1 = fmaf(kv[j + 1], base[offs[j + 1]], a1);
            a2 = fmaf(kv[j + 2], base[offs[j + 2]], a2);
            a3 = fmaf(kv[j + 3], base[offs[j + 3]], a3);
        }
        a0 = fmaf(kv[16], base[offs[16]], a0);
        a1 = fmaf(kv[17], base[offs[17]], a1);
        float acc = (a0 + a1) + (a2 + a3);
        if (l == 0) acc = fmaf(kt, base[16 * LDSW + 16], acc);  // e = 288 tail

        // butterfly sum over the 16-lane group
        #pragma unroll
        for (int off = 8; off; off >>= 1)
            acc += __shfl_xor(acc, off, 64);

        if (l == 0)
            y[(by * TILE + ppy) * WTOT + bx * TILE + ppx] = acc;
        mn = fminf(mn, acc);
        mx = fmaxf(mx, acc);
    }

    // ---- block min/max reduce, then ONE plain store to a unique slot ----
    #pragma unroll
    for (int off = 32; off > 0; off >>= 1) {
        mn = fminf(mn, __shfl_down(mn, off, 64));
        mx = fmaxf(mx, __shfl_down(mx, off, 64));
    }
    __shared__ float smn[4], smx[4];
    const int wid = tid >> 6;
    if (lane == 0) { smn[wid] = mn; smx[wid] = mx; }
    __syncthreads();
    if (tid == 0) {
        float bmn = smn[0], bmx = smx[0];
        #pragma unroll
        for (int i = 1; i < 4; ++i) {
            bmn = fminf(bmn, smn[i]);
            bmx = fmaxf(bmx, smx[i]);
        }
        partial[gid] = make_float2(bmn, bmx);
    }
}

// fused: re-reduce the 2048 partials (16 KB, L2-hit) + transform 4 px/thread
__global__ __launch_bounds__(256) void filter_final(
    float* __restrict__ y,
    const float2* __restrict__ partial)
{
    const int tid = threadIdx.x;
    float mn = 3.4e38f, mx = -3.4e38f;
    for (int i = tid; i < NBLK; i += 256) {
        const float2 p = partial[i];
        mn = fminf(mn, p.x);
        mx = fmaxf(mx, p.y);
    }
    #pragma unroll
    for (int off = 32; off > 0; off >>= 1) {
        mn = fminf(mn, __shfl_down(mn, off, 64));
        mx = fmaxf(mx, __shfl_down(mx, off, 64));
    }
    __shared__ float smn[4], smx[4];
    const int wid = tid >> 6, lane = tid & 63;
    if (lane == 0) { smn[wid] = mn; smx[wid] = mx; }
    __syncthreads();
    __shared__ float sfin[2];
    if (tid == 0) {
        float bmn = smn[0], bmx = smx[0];
        #pragma unroll
        for (int i = 1; i < 4; ++i) {
            bmn = fminf(bmn, smn[i]);
            bmx = fmaxf(bmx, smx[i]);
        }
        sfin[0] = bmn; sfin[1] = bmx;
    }
    __syncthreads();

    const float ymin = sfin[0];
    const float rng  = fmaxf(sfin[1] - ymin, 1e-8f);
    const float smin = 100.f / (1.f + expf( 11.f));   // 100*sigmoid(-11)
    const float smax = 100.f / (1.f + expf(-9.f));    // 100*sigmoid(+9)
    const float srng = fmaxf(smax - smin, 1e-8f);

    const int base = blockIdx.x * 1024 + tid * 4;
    f32x4 v = *reinterpret_cast<const f32x4*>(&y[base]);
    #pragma unroll
    for (int i = 0; i < 4; ++i) {
        const float o1 = 100.f * (v[i] - ymin) / rng;            // in [0,100]
        const float s  = 100.f / (1.f + expf(-(TEMPERATURE * (o1 * 0.01f - THRESHOLD * 0.01f))));
        v[i] = 100.f * (s - smin) / srng;
    }
    *reinterpret_cast<f32x4*>(&y[base]) = v;
}

extern "C" void kernel_launch(void* const* d_in, const int* in_sizes, int n_in,
                              void* d_out, int out_size, void* d_ws, size_t ws_size,
                              hipStream_t stream) {
    const float* x      = (const float*)d_in[0];
    const int*   freq   = (const int*)d_in[1];
    const int*   orient = (const int*)d_in[2];
    const float* fb     = (const float*)d_in[3];
    float*       out    = (float*)d_out;       // doubles as y scratch
    float2*      partial = (float2*)d_ws;      // 2048 per-block {min,max}

    // 256 tiles x 8 slices; consecutive gid = same tile across the 8 XCDs
    filter_sliced<<<dim3(NBLK), 256, 0, stream>>>(x, freq, orient, fb, out, partial);

    // 256 blocks x 256 threads x 4 px; each block inlines the partial-reduce
    filter_final<<<(HTOT * WTOT) / 1024, 256, 0, stream>>>(out, partial);
}